// Round 1
// baseline (415.918 us; speedup 1.0000x reference)
//
#include <hip/hip_runtime.h>

#define NTOK 196
#define CDIM 768
#define BSAMP 256
#define NCLS 701

// One block per (sample, branch) task. 512 threads = 8 waves.
// Phase A: stream the 196x768 tile once, computing per-token energy M[t]
//          (wave-reduced) and per-column total sum S_all (register partials).
// Phase B: normalize (exact fp32 div like the reference), O(N^2) stable rank,
//          gap diffs with the ==0 mask, first-occurrence argmax -> k.
// Phase C: re-read only the SMALLER of {fg, bg} token sets (L2-resident),
//          derive the other side as S_all - subset. Write mean vectors to V.
__global__ __launch_bounds__(512) void sgm_kernel(const float* __restrict__ x1,
                                                  const float* __restrict__ x2,
                                                  float* __restrict__ V) {
  const int task = blockIdx.x;
  const int s  = task & 255;
  const int br = task >> 8;
  const float* __restrict__ feats = (br ? x2 : x1) + (size_t)s * (NTOK * CDIM);

  const int tid  = threadIdx.x;
  const int lane = tid & 63;
  const int wv   = tid >> 6;   // 0..7

  __shared__ float Msh[NTOK];
  __shared__ float Mn[NTOK];
  __shared__ float sortedv[NTOK];
  __shared__ int   rnk[NTOK];
  __shared__ float redmin[8], redmax[8];
  __shared__ int   kSh;
  __shared__ float partS[8][CDIM];   // per-wave partials of S_all
  __shared__ float partT[8][CDIM];   // per-wave partials of subset sum

  // ---------------- Phase A ----------------
  float4 s0 = {0,0,0,0}, s1 = {0,0,0,0}, s2 = {0,0,0,0};
  for (int t = wv; t < NTOK; t += 8) {
    const float4* p = (const float4*)(feats + (size_t)t * CDIM);
    float4 a = p[lane];
    float4 b = p[lane + 64];
    float4 c = p[lane + 128];
    s0.x += a.x; s0.y += a.y; s0.z += a.z; s0.w += a.w;
    s1.x += b.x; s1.y += b.y; s1.z += b.z; s1.w += b.w;
    s2.x += c.x; s2.y += c.y; s2.z += c.z; s2.w += c.w;
    float ssum = ((a.x + a.y) + (a.z + a.w))
               + ((b.x + b.y) + (b.z + b.w))
               + ((c.x + c.y) + (c.z + c.w));
    #pragma unroll
    for (int off = 32; off; off >>= 1) ssum += __shfl_xor(ssum, off);
    if (lane == 0) Msh[t] = ssum;
  }
  __syncthreads();

  // ---------------- Phase B ----------------
  float vmn = (tid < NTOK) ? Msh[tid] :  1e30f;
  float vmx = (tid < NTOK) ? Msh[tid] : -1e30f;
  #pragma unroll
  for (int off = 32; off; off >>= 1) {
    vmn = fminf(vmn, __shfl_xor(vmn, off));
    vmx = fmaxf(vmx, __shfl_xor(vmx, off));
  }
  if (lane == 0) { redmin[wv] = vmn; redmax[wv] = vmx; }
  __syncthreads();
  float mn = redmin[0], mx = redmax[0];
  #pragma unroll
  for (int i = 1; i < 8; i++) { mn = fminf(mn, redmin[i]); mx = fmaxf(mx, redmax[i]); }
  const float rng = mx - mn;
  if (tid < NTOK) Mn[tid] = (Msh[tid] - mn) / rng;   // exact IEEE div, like ref
  __syncthreads();

  if (tid < NTOK) {
    const float mv = Mn[tid];
    int r = 0;
    for (int u = 0; u < NTOK; u++) {
      const float o = Mn[u];
      r += (o < mv) || (o == mv && u < tid);   // stable argsort tie-break
    }
    sortedv[r] = mv;
    rnk[tid] = r;
  }
  __syncthreads();

  if (tid < 64) {
    float bd = -1.0f; int bj = NTOK;
    for (int j = lane; j < NTOK - 1; j += 64) {
      const float sj = sortedv[j];
      const float d = (sj == 0.0f) ? 0.0f : (sortedv[j + 1] - sj);
      if (d > bd || (d == bd && j < bj)) { bd = d; bj = j; }
    }
    #pragma unroll
    for (int off = 32; off; off >>= 1) {
      const float od = __shfl_xor(bd, off);
      const int   oj = __shfl_xor(bj, off);
      if (od > bd || (od == bd && oj < bj)) { bd = od; bj = oj; }
    }
    if (lane == 0) kSh = bj;   // first-occurrence argmax
  }
  __syncthreads();

  const int k = kSh;
  const bool takeFg = (k <= NTOK / 2);

  // ---------------- Phase C ----------------
  float4 t0 = {0,0,0,0}, t1 = {0,0,0,0}, t2 = {0,0,0,0};
  for (int t = wv; t < NTOK; t += 8) {
    const int r = rnk[t];
    const bool inSet = takeFg ? (r < k) : (r >= k);   // wave-uniform branch
    if (inSet) {
      const float4* p = (const float4*)(feats + (size_t)t * CDIM);
      float4 a = p[lane];
      float4 b = p[lane + 64];
      float4 c = p[lane + 128];
      t0.x += a.x; t0.y += a.y; t0.z += a.z; t0.w += a.w;
      t1.x += b.x; t1.y += b.y; t1.z += b.z; t1.w += b.w;
      t2.x += c.x; t2.y += c.y; t2.z += c.z; t2.w += c.w;
    }
  }

  const int base = lane * 4;
  *(float4*)&partS[wv][base      ] = s0;
  *(float4*)&partS[wv][base + 256] = s1;
  *(float4*)&partS[wv][base + 512] = s2;
  *(float4*)&partT[wv][base      ] = t0;
  *(float4*)&partT[wv][base + 256] = t1;
  *(float4*)&partT[wv][base + 512] = t2;
  __syncthreads();

  const float fgc = (float)(k > 1 ? k : 1);
  const float bgc = (float)((NTOK - k) > 1 ? (NTOK - k) : 1);
  const size_t rowFg = (size_t)(2 * br + 1) * BSAMP + s;
  const size_t rowBg = (size_t)(2 * br    ) * BSAMP + s;
  for (int c = tid; c < CDIM; c += 512) {
    float S = 0.0f, T = 0.0f;
    #pragma unroll
    for (int w = 0; w < 8; w++) { S += partS[w][c]; T += partT[w][c]; }
    float fg, bg;
    if (takeFg) { fg = T;     bg = S - T; }
    else        { bg = T;     fg = S - T; }
    V[rowFg * CDIM + c] = fg / fgc;
    V[rowBg * CDIM + c] = bg / bgc;
  }
}

// V[1024,768] @ W[768,701] + b -> out[1024,701]
// 64x64 tile per block, 256 threads, 4x4 register tile, BK=16 LDS staging.
__global__ __launch_bounds__(256) void gemm_kernel(const float* __restrict__ V,
                                                   const float* __restrict__ W,
                                                   const float* __restrict__ bias,
                                                   float* __restrict__ out) {
  const int col0 = blockIdx.x * 64;
  const int row0 = blockIdx.y * 64;
  __shared__ float Vt[16][68];   // [kk][row], padded
  __shared__ float Wt[16][68];   // [kk][col], padded

  const int tid = threadIdx.x;
  const int tx = tid & 15, ty = tid >> 4;
  float acc[4][4];
  #pragma unroll
  for (int i = 0; i < 4; i++)
    #pragma unroll
    for (int j = 0; j < 4; j++) acc[i][j] = 0.0f;

  const int vr = tid >> 2;        // 0..63 (row within tile)
  const int vk = (tid & 3) * 4;   // 0,4,8,12 (k offset)

  for (int k0 = 0; k0 < CDIM; k0 += 16) {
    const float4 va = *(const float4*)&V[(size_t)(row0 + vr) * CDIM + k0 + vk];
    Vt[vk + 0][vr] = va.x;
    Vt[vk + 1][vr] = va.y;
    Vt[vk + 2][vr] = va.z;
    Vt[vk + 3][vr] = va.w;
    #pragma unroll
    for (int i = 0; i < 4; i++) {
      const int e = tid + i * 256;
      const int kk = e >> 6, c = e & 63;
      const int col = col0 + c;
      Wt[kk][c] = (col < NCLS) ? W[(size_t)(k0 + kk) * NCLS + col] : 0.0f;
    }
    __syncthreads();
    #pragma unroll
    for (int kk = 0; kk < 16; kk++) {
      const float4 a = *(const float4*)&Vt[kk][ty * 4];
      const float4 b = *(const float4*)&Wt[kk][tx * 4];
      const float av[4] = {a.x, a.y, a.z, a.w};
      const float bv[4] = {b.x, b.y, b.z, b.w};
      #pragma unroll
      for (int i = 0; i < 4; i++)
        #pragma unroll
        for (int j = 0; j < 4; j++) acc[i][j] += av[i] * bv[j];
    }
    __syncthreads();
  }

  #pragma unroll
  for (int i = 0; i < 4; i++) {
    const int r = row0 + ty * 4 + i;
    #pragma unroll
    for (int j = 0; j < 4; j++) {
      const int col = col0 + tx * 4 + j;
      if (col < NCLS) out[(size_t)r * NCLS + col] = acc[i][j] + bias[col];
    }
  }
}

extern "C" void kernel_launch(void* const* d_in, const int* in_sizes, int n_in,
                              void* d_out, int out_size, void* d_ws, size_t ws_size,
                              hipStream_t stream) {
  const float* x1 = (const float*)d_in[0];
  const float* x2 = (const float*)d_in[1];
  const float* W  = (const float*)d_in[2];
  const float* b  = (const float*)d_in[3];
  float* out = (float*)d_out;
  float* V = (float*)d_ws;   // 4*256*768 fp32 = 3 MB scratch

  sgm_kernel<<<512, 512, 0, stream>>>(x1, x2, V);
  gemm_kernel<<<dim3(11, 16), 256, 0, stream>>>(V, W, b, out);
}

// Round 2
// 349.834 us; speedup vs baseline: 1.1889x; 1.1889x over previous
//
#include <hip/hip_runtime.h>
#include <hip/hip_bf16.h>

#define NTOK 196
#define CDIM 768
#define BSAMP 256
#define NCLS 701
#define NCLSP 704

typedef __attribute__((ext_vector_type(8))) short bf16x8;
typedef __attribute__((ext_vector_type(4))) float f32x4;

__device__ __forceinline__ void add4(float4& a, const float4& b) {
  a.x += b.x; a.y += b.y; a.z += b.z; a.w += b.w;
}

// One block per (sample, branch) task. 512 threads = 8 waves.
// Phase A: batched 4-token loads (12 independent float4 loads in flight per
//          wave) -> column-sum register partials + per-token energies via 4
//          interleaved shuffle chains (arithmetic bitwise-identical to R1).
// Phase B: normalize, O(N^2) stable rank, gap argmax -> k (unchanged).
// Phase C: compact the SMALLER token set into an LDS list, then batched
//          4-token loads over the list; other side = S_all - subset.
// Epilogue: write mean vectors directly as bf16 for the MFMA classifier.
__global__ __launch_bounds__(512) void sgm_kernel(const float* __restrict__ x1,
                                                  const float* __restrict__ x2,
                                                  __hip_bfloat16* __restrict__ Vb) {
  const int task = blockIdx.x;
  const int s  = task & 255;
  const int br = task >> 8;
  const float* __restrict__ feats = (br ? x2 : x1) + (size_t)s * (NTOK * CDIM);

  const int tid  = threadIdx.x;
  const int lane = tid & 63;
  const int wv   = tid >> 6;   // 0..7

  __shared__ float Msh[NTOK];
  __shared__ float Mn[NTOK];
  __shared__ float sortedv[NTOK];
  __shared__ int   rnk[NTOK];
  __shared__ int   list[NTOK];
  __shared__ float redmin[8], redmax[8];
  __shared__ int   kSh;
  __shared__ int   cntSh;
  __shared__ float partS[8][CDIM];   // per-wave partials of S_all
  __shared__ float partT[8][CDIM];   // per-wave partials of subset sum

  // ---------------- Phase A (batched) ----------------
  // Wave wv owns tokens t = wv + 8*i. Process in batches of 4: tokens
  // t0, t0+8, t0+16, t0+24 with t0 = wv + 32*ib, ib = 0..5 (covers i=0..23).
  // Waves 0..3 additionally own token 192+wv.
  float4 acc[3];
  #pragma unroll
  for (int g = 0; g < 3; g++) acc[g] = make_float4(0.f, 0.f, 0.f, 0.f);

  const float* lanebase = feats + lane * 4;

  for (int ib = 0; ib < 6; ib++) {
    const int t0 = wv + ib * 32;
    const float* p = lanebase + (size_t)t0 * CDIM;
    float4 r[4][3];
    #pragma unroll
    for (int j = 0; j < 4; j++)
      #pragma unroll
      for (int g = 0; g < 3; g++)
        r[j][g] = *(const float4*)(p + j * (8 * CDIM) + g * 256);

    float e[4];
    #pragma unroll
    for (int j = 0; j < 4; j++) {
      #pragma unroll
      for (int g = 0; g < 3; g++) add4(acc[g], r[j][g]);
      e[j] = ((r[j][0].x + r[j][0].y) + (r[j][0].z + r[j][0].w))
           + ((r[j][1].x + r[j][1].y) + (r[j][1].z + r[j][1].w))
           + ((r[j][2].x + r[j][2].y) + (r[j][2].z + r[j][2].w));
    }
    #pragma unroll
    for (int off = 32; off; off >>= 1) {
      #pragma unroll
      for (int j = 0; j < 4; j++) e[j] += __shfl_xor(e[j], off);
    }
    if (lane == 0) {
      #pragma unroll
      for (int j = 0; j < 4; j++) Msh[t0 + j * 8] = e[j];
    }
  }
  if (wv < 4) {  // tail token 192+wv
    const int t = 192 + wv;
    const float* p = lanebase + (size_t)t * CDIM;
    float4 r0 = *(const float4*)(p);
    float4 r1 = *(const float4*)(p + 256);
    float4 r2 = *(const float4*)(p + 512);
    add4(acc[0], r0); add4(acc[1], r1); add4(acc[2], r2);
    float e = ((r0.x + r0.y) + (r0.z + r0.w))
            + ((r1.x + r1.y) + (r1.z + r1.w))
            + ((r2.x + r2.y) + (r2.z + r2.w));
    #pragma unroll
    for (int off = 32; off; off >>= 1) e += __shfl_xor(e, off);
    if (lane == 0) Msh[t] = e;
  }
  if (tid == 0) cntSh = 0;
  __syncthreads();

  // ---------------- Phase B ----------------
  float vmn = (tid < NTOK) ? Msh[tid] :  1e30f;
  float vmx = (tid < NTOK) ? Msh[tid] : -1e30f;
  #pragma unroll
  for (int off = 32; off; off >>= 1) {
    vmn = fminf(vmn, __shfl_xor(vmn, off));
    vmx = fmaxf(vmx, __shfl_xor(vmx, off));
  }
  if (lane == 0) { redmin[wv] = vmn; redmax[wv] = vmx; }
  __syncthreads();
  float mn = redmin[0], mx = redmax[0];
  #pragma unroll
  for (int i = 1; i < 8; i++) { mn = fminf(mn, redmin[i]); mx = fmaxf(mx, redmax[i]); }
  const float rng = mx - mn;
  if (tid < NTOK) Mn[tid] = (Msh[tid] - mn) / rng;   // exact IEEE div, like ref
  __syncthreads();

  if (tid < NTOK) {
    const float mv = Mn[tid];
    int r = 0;
    for (int u = 0; u < NTOK; u++) {
      const float o = Mn[u];
      r += (o < mv) || (o == mv && u < tid);   // stable argsort tie-break
    }
    sortedv[r] = mv;
    rnk[tid] = r;
  }
  __syncthreads();

  if (tid < 64) {
    float bd = -1.0f; int bj = NTOK;
    for (int j = lane; j < NTOK - 1; j += 64) {
      const float sj = sortedv[j];
      const float d = (sj == 0.0f) ? 0.0f : (sortedv[j + 1] - sj);
      if (d > bd || (d == bd && j < bj)) { bd = d; bj = j; }
    }
    #pragma unroll
    for (int off = 32; off; off >>= 1) {
      const float od = __shfl_xor(bd, off);
      const int   oj = __shfl_xor(bj, off);
      if (od > bd || (od == bd && oj < bj)) { bd = od; bj = oj; }
    }
    if (lane == 0) kSh = bj;   // first-occurrence argmax
  }
  __syncthreads();

  const int k = kSh;
  const bool takeFg = (k <= NTOK / 2);

  // compact the smaller set's token indices (order irrelevant for the sum)
  if (tid < NTOK) {
    const int r = rnk[tid];
    const bool inSet = takeFg ? (r < k) : (r >= k);
    if (inSet) { int p = atomicAdd(&cntSh, 1); list[p] = tid; }
  }
  __syncthreads();
  const int m = cntSh;

  // ---------------- Phase C (batched over list) ----------------
  float4 tacc[3];
  #pragma unroll
  for (int g = 0; g < 3; g++) tacc[g] = make_float4(0.f, 0.f, 0.f, 0.f);

  for (int i0 = wv * 4; i0 < m; i0 += 32) {
    const int nb = m - i0;   // wave-uniform; >=1
    float4 r[4][3];
    #pragma unroll
    for (int j = 0; j < 4; j++) {
      if (j < nb) {
        const int t = list[i0 + j];
        const float* p = lanebase + (size_t)t * CDIM;
        #pragma unroll
        for (int g = 0; g < 3; g++) r[j][g] = *(const float4*)(p + g * 256);
      }
    }
    #pragma unroll
    for (int j = 0; j < 4; j++) {
      if (j < nb) {
        #pragma unroll
        for (int g = 0; g < 3; g++) add4(tacc[g], r[j][g]);
      }
    }
  }

  const int base = lane * 4;
  #pragma unroll
  for (int g = 0; g < 3; g++) {
    *(float4*)&partS[wv][base + g * 256] = acc[g];
    *(float4*)&partT[wv][base + g * 256] = tacc[g];
  }
  __syncthreads();

  const float fgc = (float)(k > 1 ? k : 1);
  const float bgc = (float)((NTOK - k) > 1 ? (NTOK - k) : 1);
  const size_t rowFg = (size_t)(2 * br + 1) * BSAMP + s;
  const size_t rowBg = (size_t)(2 * br    ) * BSAMP + s;
  for (int c = tid; c < CDIM; c += 512) {
    float S = 0.0f, T = 0.0f;
    #pragma unroll
    for (int w = 0; w < 8; w++) { S += partS[w][c]; T += partT[w][c]; }
    float fg, bg;
    if (takeFg) { fg = T;     bg = S - T; }
    else        { bg = T;     fg = S - T; }
    Vb[rowFg * CDIM + c] = __float2bfloat16(fg / fgc);
    Vb[rowBg * CDIM + c] = __float2bfloat16(bg / bgc);
  }
}

// W [768][701] fp32 -> WT [704][768] bf16 (rows 701..703 zero-padded).
__global__ __launch_bounds__(256) void wt_kernel(const float* __restrict__ W,
                                                 __hip_bfloat16* __restrict__ WT) {
  __shared__ float tile[32][33];
  const int c0 = blockIdx.x * 32;   // class cols of W
  const int k0 = blockIdx.y * 32;   // k rows of W
  const int tx = threadIdx.x & 31;
  const int ty = threadIdx.x >> 5;  // 0..7
  #pragma unroll
  for (int i = 0; i < 4; i++) {
    const int kr = ty + i * 8;      // 0..31
    const int c = c0 + tx;
    tile[kr][tx] = (c < NCLS) ? W[(size_t)(k0 + kr) * NCLS + c] : 0.0f;
  }
  __syncthreads();
  #pragma unroll
  for (int i = 0; i < 4; i++) {
    const int cr = ty + i * 8;      // class row within tile
    const int cls = c0 + cr;        // < 704 always
    WT[(size_t)cls * CDIM + k0 + tx] = __float2bfloat16(tile[tx][cr]);
  }
}

// Vb [1024][768] bf16 (row-major, K contiguous) x WT [704][768] bf16
// -> out [1024][701] fp32 (+bias). One 16x16 tile per wave via
// mfma_f32_16x16x32_bf16; K-loop fully unrolled (24 MFMA).
// A-frag: lane holds A[m=lane&15][k=(lane>>4)*8 + j]  (16B contiguous)
// B-frag: lane holds B[k=(lane>>4)*8 + j][n=lane&15]  (= WT row, contiguous)
// C/D  : col=lane&15, row=(lane>>4)*4+reg   [m89/m91-verified]
__global__ __launch_bounds__(256) void mfma_gemm(const __hip_bfloat16* __restrict__ Vb,
                                                 const __hip_bfloat16* __restrict__ WT,
                                                 const float* __restrict__ bias,
                                                 float* __restrict__ out) {
  const int w = blockIdx.x * 4 + (threadIdx.x >> 6);   // 0..2815
  const int lane = threadIdx.x & 63;
  const int tr = w / (NCLSP / 16);   // 0..63
  const int tc = w % (NCLSP / 16);   // 0..43
  const int m0 = tr * 16;
  const int n0 = tc * 16;
  const int ko = (lane >> 4) * 8;

  const short* aptr = (const short*)Vb + (size_t)(m0 + (lane & 15)) * CDIM + ko;
  const short* bptr = (const short*)WT + (size_t)(n0 + (lane & 15)) * CDIM + ko;

  f32x4 acc = {0.f, 0.f, 0.f, 0.f};
  #pragma unroll
  for (int k0 = 0; k0 < CDIM; k0 += 32) {
    const bf16x8 af = *(const bf16x8*)(aptr + k0);
    const bf16x8 bf = *(const bf16x8*)(bptr + k0);
    acc = __builtin_amdgcn_mfma_f32_16x16x32_bf16(af, bf, acc, 0, 0, 0);
  }

  const int crow = m0 + (lane >> 4) * 4;
  const int ccol = n0 + (lane & 15);
  if (ccol < NCLS) {
    const float bv = bias[ccol];
    #pragma unroll
    for (int r = 0; r < 4; r++)
      out[(size_t)(crow + r) * NCLS + ccol] = acc[r] + bv;
  }
}

extern "C" void kernel_launch(void* const* d_in, const int* in_sizes, int n_in,
                              void* d_out, int out_size, void* d_ws, size_t ws_size,
                              hipStream_t stream) {
  const float* x1 = (const float*)d_in[0];
  const float* x2 = (const float*)d_in[1];
  const float* W  = (const float*)d_in[2];
  const float* b  = (const float*)d_in[3];
  float* out = (float*)d_out;

  __hip_bfloat16* Vb = (__hip_bfloat16*)d_ws;                       // 1024*768*2 = 1.5 MB
  __hip_bfloat16* WT = (__hip_bfloat16*)((char*)d_ws + 1024 * CDIM * 2); // 704*768*2 = 1.08 MB

  sgm_kernel<<<512, 512, 0, stream>>>(x1, x2, Vb);
  wt_kernel<<<dim3(22, 24), 256, 0, stream>>>(W, WT);
  mfma_gemm<<<704, 256, 0, stream>>>(Vb, WT, b, out);
}